// Round 1
// 9624.440 us; speedup vs baseline: 1.5269x; 1.5269x over previous
//
#include <hip/hip_runtime.h>

#define B_ 64
#define T_ 256
#define H_ 1024
#define S_ 128
#define OBS_ 1024
#define ACT_ 32

typedef __attribute__((ext_vector_type(8))) short bf16x8;
typedef __attribute__((ext_vector_type(4))) float f32x4;

#define MFMA(a, b, c) __builtin_amdgcn_mfma_f32_16x16x32_bf16((a), (b), (c), 0, 0, 0)

__device__ __forceinline__ float bf2f(short s) {
    unsigned int u = ((unsigned int)(unsigned short)s) << 16;
    float f; __builtin_memcpy(&f, &u, 4); return f;
}
__device__ __forceinline__ short f2bf(float f) {
    unsigned int u; __builtin_memcpy(&u, &f, 4);
    unsigned int r = (u + 0x7fffu + ((u >> 16) & 1u)) >> 16;
    return (short)r;
}
__device__ __forceinline__ bf16x8 ld8(const short* p) { return *(const bf16x8*)p; }
__device__ __forceinline__ bf16x8 cvt8(const float* p) {
    bf16x8 r;
#pragma unroll
    for (int i = 0; i < 8; ++i) r[i] = f2bf(p[i]);
    return r;
}
// agent-scope (LLC-coherent) 16B load as two 8B atomics — cross-XCD safe
__device__ __forceinline__ bf16x8 lda8(const short* p) {
    const unsigned long long* q8 = (const unsigned long long*)p;
    union { unsigned long long q[2]; bf16x8 v; } u;
    u.q[0] = __hip_atomic_load(q8, __ATOMIC_RELAXED, __HIP_MEMORY_SCOPE_AGENT);
    u.q[1] = __hip_atomic_load(q8 + 1, __ATOMIC_RELAXED, __HIP_MEMORY_SCOPE_AGENT);
    return u.v;
}
__device__ __forceinline__ void sta8(short* p, unsigned long long v) {
    __hip_atomic_store((unsigned long long*)p, v, __ATOMIC_RELAXED, __HIP_MEMORY_SCOPE_AGENT);
}
__device__ __forceinline__ unsigned long long pk4(float4 v) {
    return (unsigned long long)(unsigned short)f2bf(v.x)
         | ((unsigned long long)(unsigned short)f2bf(v.y) << 16)
         | ((unsigned long long)(unsigned short)f2bf(v.z) << 32)
         | ((unsigned long long)(unsigned short)f2bf(v.w) << 48);
}
__device__ __forceinline__ float sigm(float x) { return 1.f / (1.f + __expf(-x)); }
__device__ __forceinline__ float tanh_f(float x) { return 1.f - 2.f / (__expf(2.f * x) + 1.f); }
__device__ __forceinline__ float splus(float x) { return (x > 20.f) ? x : log1pf(__expf(x)); }

// grid barrier: flag-array arrive + 64-lane gather poll. Relies on __syncthreads'
// vmcnt(0) drain (agent stores are write-through to LLC) for release semantics.
// ws poison 0xAAAAAAAA is negative as int, so epoch compare `< e` works from launch.
__device__ __forceinline__ void gridbar(int* flags, int e) {
    __syncthreads();
    if (threadIdx.x == 0)
        __hip_atomic_store(&flags[blockIdx.x * 16], e, __ATOMIC_RELAXED, __HIP_MEMORY_SCOPE_AGENT);
    if (threadIdx.x < 64) {
        while (__hip_atomic_load(&flags[threadIdx.x * 16], __ATOMIC_RELAXED,
                                 __HIP_MEMORY_SCOPE_AGENT) < e)
            __builtin_amdgcn_s_sleep(1);
    }
    __syncthreads();
}

__global__ void f2bf_arr(const float* __restrict__ src, short* __restrict__ dst, int n4) {
    int i = blockIdx.x * blockDim.x + threadIdx.x;
    if (i < n4) {
        float4 v = ((const float4*)src)[i];
        short4 o;
        o.x = f2bf(v.x); o.y = f2bf(v.y); o.z = f2bf(v.z); o.w = f2bf(v.w);
        ((short4*)dst)[i] = o;
    }
}

// obs_part[t][b][n] = obs[b,t,:] @ po_w1[:,1024:]^T + po_b1  (bf16, off critical path)
__global__ __launch_bounds__(256) void obs_gemm(
    const float* __restrict__ obs, const short* __restrict__ po_w1,
    const float* __restrict__ po_b1, short* __restrict__ part) {
    const int t = blockIdx.x;
    const int rg = threadIdx.x >> 6, lane = threadIdx.x & 63;
    const int c = lane & 15, q = lane >> 4;
    bf16x8 afr[32];
    const float* ap = obs + ((size_t)(rg * 16 + c) * T_ + t) * OBS_;
#pragma unroll
    for (int kb = 0; kb < 32; ++kb) afr[kb] = cvt8(ap + kb * 32 + q * 8);
    for (int jt = 0; jt < 64; ++jt) {
        f32x4 acc = {0.f, 0.f, 0.f, 0.f};
        const short* wgt = po_w1 + (size_t)(jt * 16 + c) * 2048 + 1024;
#pragma unroll 8
        for (int kb = 0; kb < 32; ++kb) acc = MFMA(afr[kb], ld8(wgt + kb * 32 + q * 8), acc);
        const float bias = po_b1[jt * 16 + c];
#pragma unroll
        for (int e = 0; e < 4; ++e) {
            const int br = rg * 16 + q * 4 + e;
            part[((size_t)t * 64 + br) * 1024 + jt * 16 + c] = f2bf(acc[e] + bias);
        }
    }
}

// Persistent scan: 64 blocks x 256 threads, 3 grid barriers per step.
// Phase H' (tiny): h(t) from register-carried gh accumulators (from P1' of t-1)
//                  + z/action input GEMM (K=160).
// Phase P1' (fused): poh(t) = relu(h@w1 + part)  AND  gh(t+1) = (h*keep)@w_hh,
//                  weights read from a 128 KiB LDS stage (loaded once, conflict-free
//                  lane-major fragment layout). gh accs stay in registers.
// Phase P2: posterior qm/qs/z (blocks 0..7), unchanged.
__global__ __launch_bounds__(256, 1) void rssm_scan(
    const short* __restrict__ act_bf, const unsigned char* __restrict__ resets,
    const short* __restrict__ w_ih, const short* __restrict__ w_hh,
    const float* __restrict__ b_ih, const float* __restrict__ b_hh,
    const short* __restrict__ po_w1, const short* __restrict__ po_w2,
    const float* __restrict__ po_b2, const short* __restrict__ part,
    const float* __restrict__ noise,
    int* flags, short* h_bf, short* z_bf, short* poh,
    float* __restrict__ out_h, float* __restrict__ out_qm,
    float* __restrict__ out_qs, float* __restrict__ out_z) {
    extern __shared__ __align__(16) char smem[];
    bf16x8* wlds = (bf16x8*)smem;  // [4 gates][32 kb][64 lanes] 16B frags = 128 KiB
    __shared__ __align__(16) float stg[64][20];  // pad 20: breaks 4-way bank conflict
    const int tid = threadIdx.x, bid = blockIdx.x;
    const int rg = tid >> 6, lane = tid & 63, c = lane & 15, q = lane >> 4;
    const int j0 = bid * 16, m0 = rg * 16, arow = m0 + c, n = j0 + c;
    const int srow = tid >> 2, sseg = tid & 3;
    const bf16x8 zv8 = {0, 0, 0, 0, 0, 0, 0, 0};

    // ---- one-time LDS weight stage: g0 = po_w1[n][0:1024], g1..3 = w_hh gates r,u,n
    for (int i = 0; i < 32; ++i) {
        const int fid = i * 256 + tid;           // 0..8191
        const int g = fid >> 11, kb = (fid >> 6) & 31, ln = fid & 63;
        const int cc = ln & 15, qq = ln >> 4;
        const short* src = (g == 0)
            ? po_w1 + (size_t)(j0 + cc) * 2048 + kb * 32 + qq * 8
            : w_hh + (size_t)((g - 1) * 1024 + j0 + cc) * 1024 + kb * 32 + qq * 8;
        wlds[fid] = ld8(src);
    }
    __syncthreads();

    // loop-invariant prep
    const bool rsA = resets[arow] != 0;
    bool rsR[4];
#pragma unroll
    for (int e = 0; e < 4; ++e) rsR[e] = resets[m0 + q * 4 + e] != 0;
    const short* wiR = w_ih + (size_t)n * 160;
    const short* wiU = w_ih + (size_t)(1024 + n) * 160;
    const short* wiN = w_ih + (size_t)(2048 + n) * 160;
    const float biR = b_ih[n], bhR = b_hh[n];
    const float biU = b_ih[1024 + n], bhU = b_hh[1024 + n];
    const float biN = b_ih[2048 + n], bhN = b_hh[2048 + n];
    const short* ha = h_bf + arow * 1024;
    const bf16x8* wPl = wlds;            // poh weights
    const bf16x8* wRl = wlds + 2048;     // w_hh r
    const bf16x8* wUl = wlds + 4096;     // w_hh u (update gate z)
    const bf16x8* wNl = wlds + 6144;     // w_hh n
    const int s2 = (bid < 8) ? j0 + c : 0;
    const short* wm = po_w2 + (size_t)s2 * 1024;
    const short* ws2 = po_w2 + (size_t)(128 + s2) * 1024;
    const float bM = (bid < 8) ? po_b2[s2] : 0.f;
    const float bS = (bid < 8) ? po_b2[128 + s2] : 0.f;

    f32x4 hp = {0.f, 0.f, 0.f, 0.f};                 // fp32 h carry (registers)
    f32x4 gR = {0.f, 0.f, 0.f, 0.f};                 // gh accumulators, carried
    f32x4 gU = {0.f, 0.f, 0.f, 0.f};                 // across the barrier from
    f32x4 gN = {0.f, 0.f, 0.f, 0.f};                 // P1'(t-1) into H'(t)
    f32x4 pinit;                                     // obs-part prefetch
#pragma unroll
    for (int e = 0; e < 4; ++e)
        pinit[e] = bf2f(part[((size_t)0 * 64 + m0 + q * 4 + e) * 1024 + n]);

    int ep = 1;
    for (int t = 0; t < T_; ++t) {
        // ---------- phase H': h(t) ----------
        f32x4 iR = {0.f, 0.f, 0.f, 0.f};
        f32x4 iU = iR, iN = iR;
        if (t > 0) {
            const short* za = z_bf + arow * 128;
#pragma unroll
            for (int kb = 0; kb < 4; ++kb) {
                const int k = kb * 32 + q * 8;
                bf16x8 a = rsA ? zv8 : lda8(za + k);
                iR = MFMA(a, ld8(wiR + k), iR);
                iU = MFMA(a, ld8(wiU + k), iU);
                iN = MFMA(a, ld8(wiN + k), iN);
            }
            const int k = q * 8;
            bf16x8 a2 = ld8(act_bf + (size_t)arow * (T_ * ACT_) + (size_t)(t - 1) * ACT_ + k);
            iR = MFMA(a2, ld8(wiR + 128 + k), iR);
            iU = MFMA(a2, ld8(wiU + 128 + k), iU);
            iN = MFMA(a2, ld8(wiN + 128 + k), iN);
        }
#pragma unroll
        for (int e = 0; e < 4; ++e) {
            const float hpv = (t > 0 && rsR[e]) ? 0.f : hp[e];
            const float r = sigm(iR[e] + gR[e] + biR + bhR);
            const float u = sigm(iU[e] + gU[e] + biU + bhU);
            const float nn = tanh_f(iN[e] + biN + r * (gN[e] + bhN));
            const float hv = (1.f - u) * nn + u * hpv;
            hp[e] = hv;
            stg[m0 + q * 4 + e][c] = hv;
        }
        __syncthreads();
        {
            float4 hv4 = *(const float4*)&stg[srow][sseg * 4];
            sta8(h_bf + srow * 1024 + j0 + sseg * 4, pk4(hv4));
            *(float4*)(out_h + (size_t)srow * (T_ * H_) + (size_t)t * H_ + j0 + sseg * 4) = hv4;
        }
        gridbar(flags, ep++);
        // ---------- phase P1': poh(t) + gh(t+1), weights from LDS ----------
        {
            f32x4 accP = pinit;
            f32x4 nR = {0.f, 0.f, 0.f, 0.f};
            f32x4 nU = nR, nN = nR;
#pragma unroll 8
            for (int kb = 0; kb < 32; ++kb) {
                const int k = kb * 32 + q * 8;
                bf16x8 a = lda8(ha + k);
                bf16x8 am = rsA ? zv8 : a;       // gh uses masked h; poh uses raw h
                accP = MFMA(a, wPl[kb * 64 + lane], accP);
                nR = MFMA(am, wRl[kb * 64 + lane], nR);
                nU = MFMA(am, wUl[kb * 64 + lane], nU);
                nN = MFMA(am, wNl[kb * 64 + lane], nN);
            }
            gR = nR; gU = nU; gN = nN;
#pragma unroll
            for (int e = 0; e < 4; ++e) stg[m0 + q * 4 + e][c] = fmaxf(accP[e], 0.f);
        }
        if (t + 1 < T_) {  // prefetch next step's obs-part (constant data)
#pragma unroll
            for (int e = 0; e < 4; ++e)
                pinit[e] = bf2f(part[((size_t)(t + 1) * 64 + m0 + q * 4 + e) * 1024 + n]);
        }
        float nz[4];
        if (bid < 8) {     // prefetch noise for P2 (constant data)
#pragma unroll
            for (int e = 0; e < 4; ++e)
                nz[e] = noise[(size_t)(m0 + q * 4 + e) * (T_ * S_) + (size_t)t * S_ + s2];
        }
        __syncthreads();
        {
            float4 v4 = *(const float4*)&stg[srow][sseg * 4];
            sta8(poh + srow * 1024 + j0 + sseg * 4, pk4(v4));
        }
        gridbar(flags, ep++);
        // ---------- phase P2: qm/qs/z (blocks 0..7) ----------
        if (bid < 8) {
            f32x4 aM = {0.f, 0.f, 0.f, 0.f};
            f32x4 aS = aM;
            const short* pa = poh + arow * 1024;
#pragma unroll 8
            for (int kb = 0; kb < 32; ++kb) {
                const int k = kb * 32 + q * 8;
                bf16x8 a = lda8(pa + k);
                aM = MFMA(a, ld8(wm + k), aM);
                aS = MFMA(a, ld8(ws2 + k), aS);
            }
#pragma unroll
            for (int e = 0; e < 4; ++e) {
                const int row = m0 + q * 4 + e;
                const float qm = aM[e] + bM;
                const float qs = splus(aS[e] + bS) + 1e-6f;
                stg[row][c] = qm + qs * nz[e];
                out_qm[(size_t)row * (S_ * T_) + (size_t)s2 * T_ + t] = qm;
                out_qs[(size_t)row * (S_ * T_) + (size_t)s2 * T_ + t] = qs;
            }
            __syncthreads();
            {
                float4 z4 = *(const float4*)&stg[srow][sseg * 4];
                *(float4*)(out_z + (size_t)srow * (T_ * S_) + (size_t)t * S_ + j0 + sseg * 4) = z4;
                sta8(z_bf + srow * 128 + j0 + sseg * 4, pk4(z4));
            }
        }
        gridbar(flags, ep++);
    }
}

// Batched prior MLP over all B*T rows (off critical path)
__global__ __launch_bounds__(256) void prior_mlp(
    const float* __restrict__ hseq, const short* __restrict__ pr_w1,
    const float* __restrict__ pr_b1, const short* __restrict__ pr_w2,
    const float* __restrict__ pr_b2, float* __restrict__ out_pm,
    float* __restrict__ out_ps) {
    __shared__ __align__(16) short hid[64][512];
    const int w = threadIdx.x >> 6;
    const int lane = threadIdx.x & 63;
    const int c = lane & 15, q = lane >> 4;
    const long rb0 = (long)blockIdx.x * 64;
    bf16x8 afr[32];
    const float* ap = hseq + (rb0 + w * 16 + c) * 1024;
#pragma unroll
    for (int kb = 0; kb < 32; ++kb) afr[kb] = cvt8(ap + kb * 32 + q * 8);
    for (int jt = 0; jt < 32; ++jt) {
        f32x4 acc = {0.f, 0.f, 0.f, 0.f};
        const short* wgt = pr_w1 + (size_t)(jt * 16 + c) * 1024;
#pragma unroll 8
        for (int kb = 0; kb < 32; ++kb) acc = MFMA(afr[kb], ld8(wgt + kb * 32 + q * 8), acc);
        const float bias = pr_b1[jt * 16 + c];
#pragma unroll
        for (int e = 0; e < 4; ++e)
            hid[w * 16 + q * 4 + e][jt * 16 + c] = f2bf(fmaxf(acc[e] + bias, 0.f));
    }
    __syncthreads();
    bf16x8 afr2[16];
#pragma unroll
    for (int kb = 0; kb < 16; ++kb) afr2[kb] = *(const bf16x8*)(&hid[w * 16 + c][kb * 32 + q * 8]);
    for (int jt = 0; jt < 16; ++jt) {
        f32x4 acc = {0.f, 0.f, 0.f, 0.f};
        const short* wgt = pr_w2 + (size_t)(jt * 16 + c) * 512;
#pragma unroll 8
        for (int kb = 0; kb < 16; ++kb) acc = MFMA(afr2[kb], ld8(wgt + kb * 32 + q * 8), acc);
        const int col = jt * 16 + c;
#pragma unroll
        for (int e = 0; e < 4; ++e) {
            const long rgidx = rb0 + w * 16 + q * 4 + e;
            const int b_ = (int)(rgidx >> 8), t_ = (int)(rgidx & 255);
            if (col < S_) {
                out_pm[(size_t)b_ * (S_ * T_) + (size_t)col * T_ + t_] = acc[e] + pr_b2[col];
            } else {
                out_ps[(size_t)b_ * (S_ * T_) + (size_t)(col - S_) * T_ + t_] =
                    splus(acc[e] + pr_b2[col]) + 1e-6f;
            }
        }
    }
}

extern "C" void kernel_launch(void* const* d_in, const int* in_sizes, int n_in,
                              void* d_out, int out_size, void* d_ws, size_t ws_size,
                              hipStream_t stream) {
    const float* obs = (const float*)d_in[0];
    const float* action = (const float*)d_in[1];
    const unsigned char* resets = (const unsigned char*)d_in[2];
    const float* noise = (const float*)d_in[3];
    const float* w_ih = (const float*)d_in[4];
    const float* w_hh = (const float*)d_in[5];
    const float* b_ih = (const float*)d_in[6];
    const float* b_hh = (const float*)d_in[7];
    const float* pr_w1 = (const float*)d_in[8];
    const float* pr_b1 = (const float*)d_in[9];
    const float* pr_w2 = (const float*)d_in[10];
    const float* pr_b2 = (const float*)d_in[11];
    const float* po_w1 = (const float*)d_in[12];
    const float* po_b1 = (const float*)d_in[13];
    const float* po_w2 = (const float*)d_in[14];
    const float* po_b2 = (const float*)d_in[15];

    float* out = (float*)d_out;
    const size_t BST = (size_t)B_ * S_ * T_;  // 2097152
    float* out_pm = out;
    float* out_ps = out + BST;
    float* out_qm = out + 2 * BST;
    float* out_qs = out + 3 * BST;
    float* out_h = out + 4 * BST;
    float* out_z = out + 4 * BST + (size_t)B_ * T_ * H_;

    char* w = (char*)d_ws;
    int* flags = (int*)w;                      // 4096 B (64 x 64B)
    short* h_bf = (short*)(w + 4096);          // 64x1024 (single buffer now)
    short* z_bf = (short*)(w + 266240);        // 64x128
    short* poh = (short*)(w + 282624);         // 64x1024
    short* act_bf = (short*)(w + 413696);      // 64x256x32
    short* w_ih_bf = (short*)(w + 1462272);    // 3072x160
    short* w_hh_bf = (short*)(w + 2445312);    // 3072x1024
    short* po_w1_bf = (short*)(w + 8736768);   // 1024x2048
    short* po_w2_bf = (short*)(w + 12931072);  // 256x1024
    short* pr_w1_bf = (short*)(w + 13455360);  // 512x1024
    short* pr_w2_bf = (short*)(w + 14503936);  // 256x512
    short* part = (short*)(w + 14766080);      // [T][64][1024] bf16 = 32 MB

    static bool attr_set = false;
    if (!attr_set) {
        hipFuncSetAttribute(reinterpret_cast<const void*>(&rssm_scan),
                            hipFuncAttributeMaxDynamicSharedMemorySize, 131072);
        attr_set = true;
    }

    auto cvt = [&](const float* s, short* d, int n) {
        int n4 = n / 4;
        f2bf_arr<<<dim3((n4 + 255) / 256), 256, 0, stream>>>(s, d, n4);
    };
    cvt(action, act_bf, B_ * T_ * ACT_);
    cvt(w_ih, w_ih_bf, 3 * H_ * (S_ + ACT_));
    cvt(w_hh, w_hh_bf, 3 * H_ * H_);
    cvt(po_w1, po_w1_bf, 1024 * 2048);
    cvt(po_w2, po_w2_bf, 256 * 1024);
    cvt(pr_w1, pr_w1_bf, 512 * 1024);
    cvt(pr_w2, pr_w2_bf, 256 * 512);

    obs_gemm<<<dim3(256), 256, 0, stream>>>(obs, po_w1_bf, po_b1, part);

    rssm_scan<<<dim3(64), 256, 131072, stream>>>(
        act_bf, resets, w_ih_bf, w_hh_bf, b_ih, b_hh,
        po_w1_bf, po_w2_bf, po_b2, part, noise,
        flags, h_bf, z_bf, poh, out_h, out_qm, out_qs, out_z);

    prior_mlp<<<dim3(256), 256, 0, stream>>>(out_h, pr_w1_bf, pr_b1, pr_w2_bf, pr_b2,
                                             out_pm, out_ps);
}